// Round 3
// baseline (5323.634 us; speedup 1.0000x reference)
//
#include <hip/hip_runtime.h>
#include <cstddef>
#include <cstdint>

// ---------------------------------------------------------------------------
// LSTM layer: T=512, B=64, I=512, H=512.
// Phase 1: xW = x @ W + b  (bf16 MFMA GEMM, M=32768, K=512, N=2048)
// Phase 2: persistent recurrent kernel, 32 WGs, U-slices register-resident.
//   R3: fix R2's LDS staging (covered only 1/4 of the tile -> NaN).
//       Keeps: distributed per-WG epoch flags, xW prefetch, ping-pong abuf.
// ---------------------------------------------------------------------------

#define T_STEPS 512
#define NB      64      // batch
#define HID     512
#define G4      2048    // 4*H
#define KDIM    512
#define NWG     32      // recurrent workgroups; each owns 16 hidden units
#define FLAG_STRIDE 32  // unsigned stride between flags = 128 B (own line each)

typedef short bf16x8 __attribute__((ext_vector_type(8)));
typedef float f32x4  __attribute__((ext_vector_type(4)));

__device__ __forceinline__ float bf2f(unsigned short s) {
    unsigned u = ((unsigned)s) << 16;
    float f; __builtin_memcpy(&f, &u, 4); return f;
}
__device__ __forceinline__ unsigned short f2bf(float f) {
    unsigned u; __builtin_memcpy(&u, &f, 4);
    u = (u + 0x7FFFu + ((u >> 16) & 1u)) >> 16;
    return (unsigned short)u;
}

// ---------------- kernel 1: cast x to bf16 (also zero the epoch flags) -----
__global__ void cast_x_kernel(const float* __restrict__ x,
                              unsigned short* __restrict__ o,
                              unsigned* __restrict__ flags) {
    if (blockIdx.x == 0 && threadIdx.x < NWG)
        flags[threadIdx.x * FLAG_STRIDE] = 0u;
    size_t i = (size_t)blockIdx.x * blockDim.x + threadIdx.x;  // one float4 each
    float4 v = ((const float4*)x)[i];
    ushort4 r;
    r.x = f2bf(v.x); r.y = f2bf(v.y); r.z = f2bf(v.z); r.w = f2bf(v.w);
    ((ushort4*)o)[i] = r;
}

// ---------------- kernel 2: transpose+cast [512][2048] f32 -> [2048][512] bf16
__global__ void transpose_cast(const float* __restrict__ src,
                               unsigned short* __restrict__ dst) {
    __shared__ float tile[64][65];
    const int n0 = blockIdx.x * 64;   // 32 tiles
    const int k0 = blockIdx.y * 64;   // 8 tiles
    const int c  = threadIdx.x & 63;
    const int r0 = threadIdx.x >> 6;  // 0..3
    for (int p = 0; p < 16; ++p) {
        int r = p * 4 + r0;           // k-local
        tile[r][c] = src[(size_t)(k0 + r) * G4 + n0 + c];
    }
    __syncthreads();
    for (int p = 0; p < 16; ++p) {
        int r = p * 4 + r0;           // n-local
        dst[(size_t)(n0 + r) * KDIM + k0 + c] = f2bf(tile[c][r]);
    }
}

// ---------------- kernel 3: bf16 MFMA GEMM: C[M][2048] = A[M][512]*Bt^T + bias
__global__ __launch_bounds__(256) void gemm_xw(
        const unsigned short* __restrict__ A,
        const unsigned short* __restrict__ Bt,
        const float* __restrict__ bias,
        unsigned short* __restrict__ C) {
    __shared__ unsigned short As[128][56];
    __shared__ unsigned short Bs[128][56];
    const int m0 = blockIdx.x * 128;
    const int n0 = blockIdx.y * 128;
    const int tid = threadIdx.x;
    const int lane = tid & 63, wave = tid >> 6;
    const int quad = lane >> 4, l16 = lane & 15;
    const int wm = (wave >> 1) * 64, wn = (wave & 1) * 64;
    f32x4 acc[4][4];
    for (int i = 0; i < 4; ++i)
        for (int j = 0; j < 4; ++j) acc[i][j] = (f32x4)0.0f;
    const int srow = tid >> 2, scol = (tid & 3) * 8;
    for (int k0 = 0; k0 < KDIM; k0 += 32) {
        __syncthreads();
        for (int p = 0; p < 2; ++p) {
            int row = p * 64 + srow;
            *(uint4*)&As[row][scol] =
                *(const uint4*)&A[(size_t)(m0 + row) * KDIM + k0 + scol];
            *(uint4*)&Bs[row][scol] =
                *(const uint4*)&Bt[(size_t)(n0 + row) * KDIM + k0 + scol];
        }
        __syncthreads();
        bf16x8 af[4], bf[4];
        for (int i = 0; i < 4; ++i)
            af[i] = *(const bf16x8*)&As[wm + i * 16 + l16][quad * 8];
        for (int j = 0; j < 4; ++j)
            bf[j] = *(const bf16x8*)&Bs[wn + j * 16 + l16][quad * 8];
        for (int i = 0; i < 4; ++i)
            for (int j = 0; j < 4; ++j)
                acc[i][j] = __builtin_amdgcn_mfma_f32_16x16x32_bf16(
                    af[i], bf[j], acc[i][j], 0, 0, 0);
    }
    for (int i = 0; i < 4; ++i)
        for (int j = 0; j < 4; ++j) {
            int col = n0 + wn + j * 16 + l16;
            float bv = bias[col];
            for (int r = 0; r < 4; ++r) {
                int row = m0 + wm + i * 16 + quad * 4 + r;
                C[(size_t)row * G4 + col] = f2bf(acc[i][j][r] + bv);
            }
        }
}

// ---------------- distributed flag wait: lanes 0..31 poll the 32 flags ------
__device__ __forceinline__ void wait_flags(unsigned* flags, unsigned target) {
    const int lane = threadIdx.x & 63;
    if (lane < NWG) {
        while (__hip_atomic_load(&flags[lane * FLAG_STRIDE], __ATOMIC_RELAXED,
                                 __HIP_MEMORY_SCOPE_AGENT) < target) {
            __builtin_amdgcn_s_sleep(2);
        }
    }
    __builtin_amdgcn_fence(__ATOMIC_ACQUIRE, "agent");
}

// ---------------- kernel 4: persistent recurrence -------------------------
// WG g owns hidden units [g*16, g*16+16). Wave w = gate w (u,f,o,c).
__global__ __launch_bounds__(256) void lstm_rec(
        const unsigned short* __restrict__ xW,   // [M][2048] bf16
        const unsigned short* __restrict__ Ut,   // [2048][512] bf16
        const float* __restrict__ a0,            // [64][512] f32
        float* __restrict__ out,                 // [T*64][512] f32
        unsigned short* __restrict__ abuf,       // [2][64][512] bf16
        unsigned* __restrict__ flags) {
    __shared__ unsigned short a_lds[64][264];    // half-K staging (256 used)
    __shared__ float gbuf[4][64][17];            // gate exchange
    const int g   = blockIdx.x;
    const int tid = threadIdx.x;
    const int wave = tid >> 6;                   // gate index
    const int lane = tid & 63;
    const int quad = lane >> 4, l16 = lane & 15;
    const int j0 = g * 16;

    // --- register-resident B fragments (loaded once; reused 512 steps) ---
    bf16x8 bq[16];
    {
        const unsigned short* urow =
            Ut + (size_t)(wave * HID + j0 + l16) * KDIM + quad * 8;
        for (int s = 0; s < 16; ++s)
            bq[s] = *(const bf16x8*)(urow + s * 32);
    }
    // --- per-thread cell state: thread owns (b_own, jj0..jj0+3) ---
    const int b_own = tid >> 2;
    const int jj0   = (tid & 3) * 4;
    float aown[4];
    {
        const float4 v = *(const float4*)&a0[(size_t)b_own * HID + j0 + jj0];
        aown[0] = v.x; aown[1] = v.y; aown[2] = v.z; aown[3] = v.w;
        union { uint2 v2; unsigned short s[4]; } pk;
        for (int i = 0; i < 4; ++i) pk.s[i] = f2bf(aown[i]);
        *(uint2*)&abuf[(size_t)b_own * HID + j0 + jj0] = pk.v2;  // version 0
    }
    __syncthreads();
    if (tid == 0) {
        __builtin_amdgcn_fence(__ATOMIC_RELEASE, "agent");
        __hip_atomic_store(&flags[g * FLAG_STRIDE], 1u, __ATOMIC_RELAXED,
                           __HIP_MEMORY_SCOPE_AGENT);
    }

    for (int t = 0; t < T_STEPS; ++t) {
        // --- prefetch this step's xW gate rows (independent of a_{t-1}) ---
        uint2 xgr[4];
        {
            const unsigned short* xp =
                xW + ((size_t)t * NB + b_own) * G4 + j0 + jj0;
#pragma unroll
            for (int w = 0; w < 4; ++w)
                xgr[w] = *(const uint2*)(xp + (size_t)w * HID);
        }
        // --- wait for version t (= a_{t-1}) from all WGs ---
        wait_flags(flags, (unsigned)(t + 1));

        const unsigned short* acur = abuf + (size_t)(t & 1) * (NB * HID);
        unsigned short* anxt = abuf + (size_t)((t + 1) & 1) * (NB * HID);
        f32x4 acc[4];
        for (int mt = 0; mt < 4; ++mt) acc[mt] = (f32x4)0.0f;
        for (int h = 0; h < 2; ++h) {            // K in two 256-halves
            if (h) __syncthreads();
            {   // stage half: 64 rows x 256 shorts = 2048 16B-chunks,
                // 8 chunks/thread; consecutive lanes -> consecutive 16B
                // (32 chunks of 8 shorts per row)
#pragma unroll
                for (int i = 0; i < 8; ++i) {
                    int c   = i * 256 + tid;     // chunk id 0..2047
                    int r   = c >> 5;            // row 0..63
                    int col = (c & 31) * 8;      // shorts 0..248
                    *(uint4*)&a_lds[r][col] = *(const uint4*)
                        (acur + (size_t)r * HID + h * 256 + col);
                }
            }
            __syncthreads();
            for (int mt = 0; mt < 4; ++mt)
                for (int s = 0; s < 8; ++s) {
                    bf16x8 af = *(const bf16x8*)
                        &a_lds[mt * 16 + l16][s * 32 + quad * 8];
                    acc[mt] = __builtin_amdgcn_mfma_f32_16x16x32_bf16(
                        af, bq[h * 8 + s], acc[mt], 0, 0, 0);
                }
        }
        // D layout: row = quad*4+reg (batch), col = l16 (unit)
        for (int mt = 0; mt < 4; ++mt)
            for (int r = 0; r < 4; ++r)
                gbuf[wave][mt * 16 + quad * 4 + r][l16] = acc[mt][r];
        __syncthreads();
        // --- gate stage (per-thread 4 units, fp32 state in regs) ---
        {
            const size_t m = (size_t)t * NB + b_own;
            float xg[4][4];
            for (int w = 0; w < 4; ++w) {
                union { uint2 v2; unsigned short s[4]; } u;
                u.v2 = xgr[w];
                for (int i = 0; i < 4; ++i) xg[w][i] = bf2f(u.s[i]);
            }
            float4 ov;
            float* ovp = &ov.x;
            union { uint2 v2; unsigned short s[4]; } pk;
            for (int i = 0; i < 4; ++i) {
                float gu = gbuf[0][b_own][jj0 + i] + xg[0][i];
                float gf = gbuf[1][b_own][jj0 + i] + xg[1][i];
                float go = gbuf[2][b_own][jj0 + i] + xg[2][i];
                float gc = gbuf[3][b_own][jj0 + i] + xg[3][i];
                float su = 1.f / (1.f + __expf(-gu));
                float sf = 1.f / (1.f + __expf(-gf));
                float so = 1.f / (1.f + __expf(-go));
                float e2 = __expf(2.f * gc);
                float tc = 1.f - 2.f / (e2 + 1.f);          // tanh(gc)
                float cc = su * tc + sf * aown[i];           // forget * a_{t-1}
                float ec = __expf(2.f * cc);
                float th = 1.f - 2.f / (ec + 1.f);           // tanh(c)
                float a  = so * th;
                aown[i] = a;
                ovp[i]  = a;
                pk.s[i] = f2bf(a);
            }
            *(float4*)&out[m * HID + j0 + jj0] = ov;
            *(uint2*)&anxt[(size_t)b_own * HID + j0 + jj0] = pk.v2;
        }
        // --- publish version t+1: own flag only (no central RMW) ---
        __syncthreads();   // drains vmcnt for all waves before the fence
        if (tid == 0) {
            __builtin_amdgcn_fence(__ATOMIC_RELEASE, "agent");
            __hip_atomic_store(&flags[g * FLAG_STRIDE], (unsigned)(t + 2),
                               __ATOMIC_RELAXED, __HIP_MEMORY_SCOPE_AGENT);
        }
    }
}

// ---------------------------------------------------------------------------
extern "C" void kernel_launch(void* const* d_in, const int* in_sizes, int n_in,
                              void* d_out, int out_size, void* d_ws, size_t ws_size,
                              hipStream_t stream) {
    (void)in_sizes; (void)n_in; (void)out_size; (void)ws_size;
    const float* x    = (const float*)d_in[0];   // [T,B,I]
    const float* a0   = (const float*)d_in[1];   // [B,H]
    const float* W    = (const float*)d_in[2];   // [I,4H]
    const float* U    = (const float*)d_in[3];   // [H,4H]
    const float* bias = (const float*)d_in[4];   // [4H]
    float* out = (float*)d_out;

    char* ws = (char*)d_ws;
    unsigned short* xbf  = (unsigned short*)(ws);                 // 33,554,432 B
    unsigned short* Wt   = (unsigned short*)(ws + 33554432);      //  2,097,152 B
    unsigned short* Ut   = (unsigned short*)(ws + 35651584);      //  2,097,152 B
    unsigned short* xWp  = (unsigned short*)(ws + 37748736);      // 134,217,728 B
    unsigned short* abuf = (unsigned short*)(ws + 171966464);     //    131,072 B
    unsigned*       flags= (unsigned*)(ws + 172097536);           //      4,096 B

    cast_x_kernel<<<16384, 256, 0, stream>>>(x, xbf, flags);
    transpose_cast<<<dim3(32, 8), 256, 0, stream>>>(W, Wt);
    transpose_cast<<<dim3(32, 8), 256, 0, stream>>>(U, Ut);
    gemm_xw<<<dim3(256, 16), 256, 0, stream>>>(xbf, Wt, bias, xWp);
    lstm_rec<<<NWG, 256, 0, stream>>>(xWp, Ut, a0, out, abuf, flags);
}

// Round 4
// 2250.548 us; speedup vs baseline: 2.3655x; 2.3655x over previous
//
#include <hip/hip_runtime.h>
#include <cstddef>
#include <cstdint>

// ---------------------------------------------------------------------------
// LSTM layer: T=512, B=64, I=512, H=512.
// Phase 1: xW = x @ W + b  (bf16 MFMA GEMM, M=32768, K=512, N=2048)
// Phase 2: persistent recurrent kernel, 32 WGs, U-slices register-resident.
//   R4: FENCELESS step loop. All cross-WG data (a-exchange) moves via
//       agent-scope relaxed atomics (sc1 -> MALL coherence point, bypasses
//       the non-coherent per-XCD L2). No buffer_wbl2 / buffer_inv per step.
//       Single full-K LDS stage per step (all staging loads in flight).
// ---------------------------------------------------------------------------

#define T_STEPS 512
#define NB      64      // batch
#define HID     512
#define G4      2048    // 4*H
#define KDIM    512
#define NWG     32      // recurrent workgroups; each owns 16 hidden units
#define FLAG_STRIDE 32  // unsigned stride between flags = 128 B (own line each)

typedef short bf16x8 __attribute__((ext_vector_type(8)));
typedef float f32x4  __attribute__((ext_vector_type(4)));

__device__ __forceinline__ float bf2f(unsigned short s) {
    unsigned u = ((unsigned)s) << 16;
    float f; __builtin_memcpy(&f, &u, 4); return f;
}
__device__ __forceinline__ unsigned short f2bf(float f) {
    unsigned u; __builtin_memcpy(&u, &f, 4);
    u = (u + 0x7FFFu + ((u >> 16) & 1u)) >> 16;
    return (unsigned short)u;
}

// ---------------- kernel 1: cast x to bf16 (also zero the epoch flags) -----
__global__ void cast_x_kernel(const float* __restrict__ x,
                              unsigned short* __restrict__ o,
                              unsigned* __restrict__ flags) {
    if (blockIdx.x == 0 && threadIdx.x < NWG)
        flags[threadIdx.x * FLAG_STRIDE] = 0u;
    size_t i = (size_t)blockIdx.x * blockDim.x + threadIdx.x;  // one float4 each
    float4 v = ((const float4*)x)[i];
    ushort4 r;
    r.x = f2bf(v.x); r.y = f2bf(v.y); r.z = f2bf(v.z); r.w = f2bf(v.w);
    ((ushort4*)o)[i] = r;
}

// ---------------- kernel 2: transpose+cast [512][2048] f32 -> [2048][512] bf16
__global__ void transpose_cast(const float* __restrict__ src,
                               unsigned short* __restrict__ dst) {
    __shared__ float tile[64][65];
    const int n0 = blockIdx.x * 64;   // 32 tiles
    const int k0 = blockIdx.y * 64;   // 8 tiles
    const int c  = threadIdx.x & 63;
    const int r0 = threadIdx.x >> 6;  // 0..3
    for (int p = 0; p < 16; ++p) {
        int r = p * 4 + r0;           // k-local
        tile[r][c] = src[(size_t)(k0 + r) * G4 + n0 + c];
    }
    __syncthreads();
    for (int p = 0; p < 16; ++p) {
        int r = p * 4 + r0;           // n-local
        dst[(size_t)(n0 + r) * KDIM + k0 + c] = f2bf(tile[c][r]);
    }
}

// ---------------- kernel 3: bf16 MFMA GEMM: C[M][2048] = A[M][512]*Bt^T + bias
__global__ __launch_bounds__(256) void gemm_xw(
        const unsigned short* __restrict__ A,
        const unsigned short* __restrict__ Bt,
        const float* __restrict__ bias,
        unsigned short* __restrict__ C) {
    __shared__ unsigned short As[128][56];
    __shared__ unsigned short Bs[128][56];
    const int m0 = blockIdx.x * 128;
    const int n0 = blockIdx.y * 128;
    const int tid = threadIdx.x;
    const int lane = tid & 63, wave = tid >> 6;
    const int quad = lane >> 4, l16 = lane & 15;
    const int wm = (wave >> 1) * 64, wn = (wave & 1) * 64;
    f32x4 acc[4][4];
    for (int i = 0; i < 4; ++i)
        for (int j = 0; j < 4; ++j) acc[i][j] = (f32x4)0.0f;
    const int srow = tid >> 2, scol = (tid & 3) * 8;
    for (int k0 = 0; k0 < KDIM; k0 += 32) {
        __syncthreads();
        for (int p = 0; p < 2; ++p) {
            int row = p * 64 + srow;
            *(uint4*)&As[row][scol] =
                *(const uint4*)&A[(size_t)(m0 + row) * KDIM + k0 + scol];
            *(uint4*)&Bs[row][scol] =
                *(const uint4*)&Bt[(size_t)(n0 + row) * KDIM + k0 + scol];
        }
        __syncthreads();
        bf16x8 af[4], bf[4];
        for (int i = 0; i < 4; ++i)
            af[i] = *(const bf16x8*)&As[wm + i * 16 + l16][quad * 8];
        for (int j = 0; j < 4; ++j)
            bf[j] = *(const bf16x8*)&Bs[wn + j * 16 + l16][quad * 8];
        for (int i = 0; i < 4; ++i)
            for (int j = 0; j < 4; ++j)
                acc[i][j] = __builtin_amdgcn_mfma_f32_16x16x32_bf16(
                    af[i], bf[j], acc[i][j], 0, 0, 0);
    }
    for (int i = 0; i < 4; ++i)
        for (int j = 0; j < 4; ++j) {
            int col = n0 + wn + j * 16 + l16;
            float bv = bias[col];
            for (int r = 0; r < 4; ++r) {
                int row = m0 + wm + i * 16 + quad * 4 + r;
                C[(size_t)row * G4 + col] = f2bf(acc[i][j][r] + bv);
            }
        }
}

// ---------------- distributed flag wait: lanes 0..31 poll the 32 flags ------
// NO acquire fence: all cross-WG data is read via sc1 atomic loads (MALL),
// so L2 staleness cannot occur. asm barrier stops compiler reordering.
__device__ __forceinline__ void wait_flags(unsigned* flags, unsigned target) {
    const int lane = threadIdx.x & 63;
    if (lane < NWG) {
        while (__hip_atomic_load(&flags[lane * FLAG_STRIDE], __ATOMIC_RELAXED,
                                 __HIP_MEMORY_SCOPE_AGENT) < target) {
            __builtin_amdgcn_s_sleep(1);
        }
    }
    __asm__ __volatile__("" ::: "memory");
}

// ---------------- kernel 4: persistent recurrence -------------------------
// WG g owns hidden units [g*16, g*16+16). Wave w = gate w (u,f,o,c).
__global__ __launch_bounds__(256) void lstm_rec(
        const unsigned short* __restrict__ xW,   // [M][2048] bf16
        const unsigned short* __restrict__ Ut,   // [2048][512] bf16
        const float* __restrict__ a0,            // [64][512] f32
        float* __restrict__ out,                 // [T*64][512] f32
        unsigned short* __restrict__ abuf,       // [2][64][512] bf16
        unsigned* __restrict__ flags) {
    __shared__ unsigned short a_lds[64][520];    // full-K staging (+16B pad)
    __shared__ float gbuf[4][64][17];            // gate exchange
    const int g   = blockIdx.x;
    const int tid = threadIdx.x;
    const int wave = tid >> 6;                   // gate index
    const int lane = tid & 63;
    const int quad = lane >> 4, l16 = lane & 15;
    const int j0 = g * 16;

    // --- register-resident B fragments (loaded once; reused 512 steps) ---
    bf16x8 bq[16];
    {
        const unsigned short* urow =
            Ut + (size_t)(wave * HID + j0 + l16) * KDIM + quad * 8;
        for (int s = 0; s < 16; ++s)
            bq[s] = *(const bf16x8*)(urow + s * 32);
    }
    // --- per-thread cell state: thread owns (b_own, jj0..jj0+3) ---
    const int b_own = tid >> 2;
    const int jj0   = (tid & 3) * 4;
    float aown[4];
    {
        const float4 v = *(const float4*)&a0[(size_t)b_own * HID + j0 + jj0];
        aown[0] = v.x; aown[1] = v.y; aown[2] = v.z; aown[3] = v.w;
        union { unsigned long long q; unsigned short s[4]; } pk;
        for (int i = 0; i < 4; ++i) pk.s[i] = f2bf(aown[i]);
        __hip_atomic_store(
            (unsigned long long*)&abuf[(size_t)b_own * HID + j0 + jj0], pk.q,
            __ATOMIC_RELAXED, __HIP_MEMORY_SCOPE_AGENT);   // version 0 -> MALL
    }
    __syncthreads();   // drains vmcnt per wave: version-0 stores are at MALL
    if (tid == 0)
        __hip_atomic_store(&flags[g * FLAG_STRIDE], 1u, __ATOMIC_RELAXED,
                           __HIP_MEMORY_SCOPE_AGENT);

    for (int t = 0; t < T_STEPS; ++t) {
        // --- prefetch this step's xW gate rows (independent of a_{t-1};
        //     plain loads: xW is read-only and L2 stays valid, no inv) ---
        uint2 xgr[4];
        {
            const unsigned short* xp =
                xW + ((size_t)t * NB + b_own) * G4 + j0 + jj0;
#pragma unroll
            for (int w = 0; w < 4; ++w)
                xgr[w] = *(const uint2*)(xp + (size_t)w * HID);
        }
        // --- wait for version t (= a_{t-1}) from all WGs ---
        wait_flags(flags, (unsigned)(t + 1));

        // --- stage a_{t-1} (full 64 KB) via sc1 atomic loads -> LDS ---
        // 8192 8B-chunks; thread loads chunks i*256+tid (consecutive lanes
        // -> consecutive 8B). Row = c>>7 (128 chunks/row), col = (c&127)*4.
        const unsigned long long* acur8 = (const unsigned long long*)
            (abuf + (size_t)(t & 1) * (NB * HID));
        unsigned long long* anxt = (unsigned long long*)
            (abuf + (size_t)((t + 1) & 1) * (NB * HID));
        unsigned long long stg[32];
#pragma unroll
        for (int i = 0; i < 32; ++i)
            stg[i] = __hip_atomic_load(&acur8[i * 256 + tid], __ATOMIC_RELAXED,
                                       __HIP_MEMORY_SCOPE_AGENT);
#pragma unroll
        for (int i = 0; i < 32; ++i) {
            int c = i * 256 + tid;
            *(unsigned long long*)&a_lds[c >> 7][(c & 127) * 4] = stg[i];
        }
        __syncthreads();

        f32x4 acc[4];
        for (int mt = 0; mt < 4; ++mt) acc[mt] = (f32x4)0.0f;
        for (int mt = 0; mt < 4; ++mt)
            for (int s = 0; s < 16; ++s) {
                bf16x8 af = *(const bf16x8*)
                    &a_lds[mt * 16 + l16][s * 32 + quad * 8];
                acc[mt] = __builtin_amdgcn_mfma_f32_16x16x32_bf16(
                    af, bq[s], acc[mt], 0, 0, 0);
            }
        // D layout: row = quad*4+reg (batch), col = l16 (unit)
        for (int mt = 0; mt < 4; ++mt)
            for (int r = 0; r < 4; ++r)
                gbuf[wave][mt * 16 + quad * 4 + r][l16] = acc[mt][r];
        __syncthreads();
        // --- gate stage (per-thread 4 units, fp32 state in regs) ---
        {
            const size_t m = (size_t)t * NB + b_own;
            float xg[4][4];
            for (int w = 0; w < 4; ++w) {
                union { uint2 v2; unsigned short s[4]; } u;
                u.v2 = xgr[w];
                for (int i = 0; i < 4; ++i) xg[w][i] = bf2f(u.s[i]);
            }
            float4 ov;
            float* ovp = &ov.x;
            union { unsigned long long q; unsigned short s[4]; } pk;
            for (int i = 0; i < 4; ++i) {
                float gu = gbuf[0][b_own][jj0 + i] + xg[0][i];
                float gf = gbuf[1][b_own][jj0 + i] + xg[1][i];
                float go = gbuf[2][b_own][jj0 + i] + xg[2][i];
                float gc = gbuf[3][b_own][jj0 + i] + xg[3][i];
                float su = 1.f / (1.f + __expf(-gu));
                float sf = 1.f / (1.f + __expf(-gf));
                float so = 1.f / (1.f + __expf(-go));
                float e2 = __expf(2.f * gc);
                float tc = 1.f - 2.f / (e2 + 1.f);          // tanh(gc)
                float cc = su * tc + sf * aown[i];           // forget * a_{t-1}
                float ec = __expf(2.f * cc);
                float th = 1.f - 2.f / (ec + 1.f);           // tanh(c)
                float a  = so * th;
                aown[i] = a;
                ovp[i]  = a;
                pk.s[i] = f2bf(a);
            }
            *(float4*)&out[m * HID + j0 + jj0] = ov;   // plain store (L2 ok)
            __hip_atomic_store(
                &anxt[((size_t)b_own * HID + j0 + jj0) >> 2], pk.q,
                __ATOMIC_RELAXED, __HIP_MEMORY_SCOPE_AGENT);  // a_t -> MALL
        }
        // --- publish version t+1 (fenceless release: barrier drains vmcnt;
        //     a_t stores are write-through sc1, already at coherence point) --
        __syncthreads();
        if (tid == 0)
            __hip_atomic_store(&flags[g * FLAG_STRIDE], (unsigned)(t + 2),
                               __ATOMIC_RELAXED, __HIP_MEMORY_SCOPE_AGENT);
    }
}

// ---------------------------------------------------------------------------
extern "C" void kernel_launch(void* const* d_in, const int* in_sizes, int n_in,
                              void* d_out, int out_size, void* d_ws, size_t ws_size,
                              hipStream_t stream) {
    (void)in_sizes; (void)n_in; (void)out_size; (void)ws_size;
    const float* x    = (const float*)d_in[0];   // [T,B,I]
    const float* a0   = (const float*)d_in[1];   // [B,H]
    const float* W    = (const float*)d_in[2];   // [I,4H]
    const float* U    = (const float*)d_in[3];   // [H,4H]
    const float* bias = (const float*)d_in[4];   // [4H]
    float* out = (float*)d_out;

    char* ws = (char*)d_ws;
    unsigned short* xbf  = (unsigned short*)(ws);                 // 33,554,432 B
    unsigned short* Wt   = (unsigned short*)(ws + 33554432);      //  2,097,152 B
    unsigned short* Ut   = (unsigned short*)(ws + 35651584);      //  2,097,152 B
    unsigned short* xWp  = (unsigned short*)(ws + 37748736);      // 134,217,728 B
    unsigned short* abuf = (unsigned short*)(ws + 171966464);     //    131,072 B
    unsigned*       flags= (unsigned*)(ws + 172097536);           //      4,096 B

    cast_x_kernel<<<16384, 256, 0, stream>>>(x, xbf, flags);
    transpose_cast<<<dim3(32, 8), 256, 0, stream>>>(W, Wt);
    transpose_cast<<<dim3(32, 8), 256, 0, stream>>>(U, Ut);
    gemm_xw<<<dim3(256, 16), 256, 0, stream>>>(xbf, Wt, bias, xWp);
    lstm_rec<<<NWG, 256, 0, stream>>>(xWp, Ut, a0, out, abuf, flags);
}

// Round 5
// 1646.900 us; speedup vs baseline: 3.2325x; 1.3665x over previous
//
#include <hip/hip_runtime.h>
#include <cstddef>
#include <cstdint>

// ---------------------------------------------------------------------------
// LSTM layer: T=512, B=64, I=512, H=512.
// Phase 1: xW = x @ W + b  (bf16 MFMA GEMM, M=32768, K=512, N=2048)
// Phase 2: persistent recurrence, R5: 2D decomposition.
//   128 WGs = 4 batch-blocks x 32 hidden-slices. WG(i,j) owns batch rows
//   [16i,16i+16) x hidden units [16j,16j+16). Exchange only within the
//   32-WG batch group. Fenceless MALL (sc1) exchange; per-WG contiguous
//   512 B publish; wave-0-only publish path; xW folded pre-gbuf.
// ---------------------------------------------------------------------------

#define T_STEPS 512
#define NB      64      // batch
#define HID     512
#define G4      2048    // 4*H
#define KDIM    512
#define BB      4       // batch blocks (16 rows each)
#define NSL     32      // hidden slices (16 units each)
#define FLAG_STRIDE 8   // uints = 32 B per flag

typedef short bf16x8 __attribute__((ext_vector_type(8)));
typedef float f32x4  __attribute__((ext_vector_type(4)));

__device__ __forceinline__ float bf2f(unsigned short s) {
    unsigned u = ((unsigned)s) << 16;
    float f; __builtin_memcpy(&f, &u, 4); return f;
}
__device__ __forceinline__ unsigned short f2bf(float f) {
    unsigned u; __builtin_memcpy(&u, &f, 4);
    u = (u + 0x7FFFu + ((u >> 16) & 1u)) >> 16;
    return (unsigned short)u;
}

// ---------------- kernel 1: cast x to bf16 (also zero the epoch flags) -----
__global__ void cast_x_kernel(const float* __restrict__ x,
                              unsigned short* __restrict__ o,
                              unsigned* __restrict__ flags) {
    if (blockIdx.x == 0 && threadIdx.x < BB * NSL)
        flags[threadIdx.x * FLAG_STRIDE] = 0u;
    size_t i = (size_t)blockIdx.x * blockDim.x + threadIdx.x;  // one float4 each
    float4 v = ((const float4*)x)[i];
    ushort4 r;
    r.x = f2bf(v.x); r.y = f2bf(v.y); r.z = f2bf(v.z); r.w = f2bf(v.w);
    ((ushort4*)o)[i] = r;
}

// ---------------- kernel 2: transpose+cast [512][2048] f32 -> [2048][512] bf16
__global__ void transpose_cast(const float* __restrict__ src,
                               unsigned short* __restrict__ dst) {
    __shared__ float tile[64][65];
    const int n0 = blockIdx.x * 64;
    const int k0 = blockIdx.y * 64;
    const int c  = threadIdx.x & 63;
    const int r0 = threadIdx.x >> 6;
    for (int p = 0; p < 16; ++p) {
        int r = p * 4 + r0;
        tile[r][c] = src[(size_t)(k0 + r) * G4 + n0 + c];
    }
    __syncthreads();
    for (int p = 0; p < 16; ++p) {
        int r = p * 4 + r0;
        dst[(size_t)(n0 + r) * KDIM + k0 + c] = f2bf(tile[c][r]);
    }
}

// ---------------- kernel 3: bf16 MFMA GEMM: C[M][2048] = A[M][512]*Bt^T + bias
__global__ __launch_bounds__(256) void gemm_xw(
        const unsigned short* __restrict__ A,
        const unsigned short* __restrict__ Bt,
        const float* __restrict__ bias,
        unsigned short* __restrict__ C) {
    __shared__ unsigned short As[128][56];
    __shared__ unsigned short Bs[128][56];
    const int m0 = blockIdx.x * 128;
    const int n0 = blockIdx.y * 128;
    const int tid = threadIdx.x;
    const int lane = tid & 63, wave = tid >> 6;
    const int quad = lane >> 4, l16 = lane & 15;
    const int wm = (wave >> 1) * 64, wn = (wave & 1) * 64;
    f32x4 acc[4][4];
    for (int i = 0; i < 4; ++i)
        for (int j = 0; j < 4; ++j) acc[i][j] = (f32x4)0.0f;
    const int srow = tid >> 2, scol = (tid & 3) * 8;
    for (int k0 = 0; k0 < KDIM; k0 += 32) {
        __syncthreads();
        for (int p = 0; p < 2; ++p) {
            int row = p * 64 + srow;
            *(uint4*)&As[row][scol] =
                *(const uint4*)&A[(size_t)(m0 + row) * KDIM + k0 + scol];
            *(uint4*)&Bs[row][scol] =
                *(const uint4*)&Bt[(size_t)(n0 + row) * KDIM + k0 + scol];
        }
        __syncthreads();
        bf16x8 af[4], bf[4];
        for (int i = 0; i < 4; ++i)
            af[i] = *(const bf16x8*)&As[wm + i * 16 + l16][quad * 8];
        for (int j = 0; j < 4; ++j)
            bf[j] = *(const bf16x8*)&Bs[wn + j * 16 + l16][quad * 8];
        for (int i = 0; i < 4; ++i)
            for (int j = 0; j < 4; ++j)
                acc[i][j] = __builtin_amdgcn_mfma_f32_16x16x32_bf16(
                    af[i], bf[j], acc[i][j], 0, 0, 0);
    }
    for (int i = 0; i < 4; ++i)
        for (int j = 0; j < 4; ++j) {
            int col = n0 + wn + j * 16 + l16;
            float bv = bias[col];
            for (int r = 0; r < 4; ++r) {
                int row = m0 + wm + i * 16 + quad * 4 + r;
                C[(size_t)row * G4 + col] = f2bf(acc[i][j][r] + bv);
            }
        }
}

// ---------------- group flag wait: lanes 0..31 poll own group's 32 flags ----
__device__ __forceinline__ void wait_flags(unsigned* gflags, unsigned target) {
    const int lane = threadIdx.x & 63;
    if (lane < NSL) {
        while (__hip_atomic_load(&gflags[lane * FLAG_STRIDE], __ATOMIC_RELAXED,
                                 __HIP_MEMORY_SCOPE_AGENT) < target) { }
    }
    __asm__ __volatile__("" ::: "memory");
}

// ---------------- kernel 4: persistent recurrence (2D split) --------------
// abuf qword layout: [parity][block i][slice j][lane l]  (l: b=l>>2, u4=l&3)
__global__ __launch_bounds__(256) void lstm_rec(
        const unsigned short* __restrict__ xW,   // [M][2048] bf16
        const unsigned short* __restrict__ Ut,   // [2048][512] bf16
        const float* __restrict__ a0,            // [64][512] f32
        float* __restrict__ out,                 // [T*64][512] f32
        unsigned short* __restrict__ abuf,       // 2*4*32*512 B = 128 KB
        unsigned* __restrict__ flags) {
    __shared__ unsigned short a_lds[16][520];    // [batch-local][k] (+pad)
    __shared__ float gbuf[4][16][17];            // [gate][batch-local][unit]
    __shared__ unsigned short alds_out[16][16];  // a_t block, bf16
    const int wgid  = blockIdx.x;
    const int i_blk = wgid >> 5;                 // batch block 0..3
    const int j_sl  = wgid & 31;                 // hidden slice 0..31
    const int tid   = threadIdx.x;
    const int wave  = tid >> 6;                  // gate index
    const int lane  = tid & 63;
    const int quad  = lane >> 4, l16 = lane & 15;
    const int j0 = j_sl * 16;
    const int b0 = i_blk * 16;

    unsigned long long* abq = (unsigned long long*)abuf;
    unsigned* gflags = flags + (size_t)i_blk * NSL * FLAG_STRIDE;

    // --- register-resident B fragments (gate `wave`, units j0..j0+16) ---
    bf16x8 bq[16];
    {
        const unsigned short* urow =
            Ut + (size_t)(wave * HID + j0 + l16) * KDIM + quad * 8;
        for (int s = 0; s < 16; ++s)
            bq[s] = *(const bf16x8*)(urow + s * 32);
    }
    // --- per-thread state: thread owns (b0+bt, j0+ut) ---
    const int bt = tid >> 4;                     // 0..15
    const int ut = tid & 15;                     // 0..15
    float aown = a0[(size_t)(b0 + bt) * HID + j0 + ut];

    // --- init publish (parity 0), wave 0 only ---
    if (wave == 0) {
        const int lb = lane >> 2, lu4 = lane & 3;
        const float4 v = *(const float4*)&a0[(size_t)(b0 + lb) * HID + j0 + lu4 * 4];
        union { unsigned long long q; unsigned short s[4]; } pk;
        pk.s[0] = f2bf(v.x); pk.s[1] = f2bf(v.y);
        pk.s[2] = f2bf(v.z); pk.s[3] = f2bf(v.w);
        __hip_atomic_store(&abq[((size_t)i_blk * NSL + j_sl) * 64 + lane], pk.q,
                           __ATOMIC_RELAXED, __HIP_MEMORY_SCOPE_AGENT);
        __asm__ __volatile__("s_waitcnt vmcnt(0)" ::: "memory");
        if (lane == 0)
            __hip_atomic_store(&gflags[j_sl * FLAG_STRIDE], 1u,
                               __ATOMIC_RELAXED, __HIP_MEMORY_SCOPE_AGENT);
    }

    for (int t = 0; t < T_STEPS; ++t) {
        // --- prefetch xW gate addends directly in MFMA D-layout ---
        // lane (quad,l16), r: row m = t*64 + b0 + quad*4 + r, col = wave*512+j0+l16
        float xg[4];
        {
            const unsigned short* xp =
                xW + ((size_t)t * NB + b0 + quad * 4) * G4 + wave * HID + j0 + l16;
#pragma unroll
            for (int r = 0; r < 4; ++r)
                xg[r] = bf2f(xp[(size_t)r * G4]);
        }
        // --- wait for own batch group's 32 producers at version t ---
        wait_flags(gflags, (unsigned)(t + 1));

        // --- stage own batch block (16 KB, contiguous) via sc1 -> LDS ---
        const size_t rbase = ((size_t)(t & 1) * BB + i_blk) * (NSL * 64);
        unsigned long long stg[8];
#pragma unroll
        for (int q = 0; q < 8; ++q)
            stg[q] = __hip_atomic_load(&abq[rbase + q * 256 + tid],
                                       __ATOMIC_RELAXED, __HIP_MEMORY_SCOPE_AGENT);
#pragma unroll
        for (int q = 0; q < 8; ++q) {
            int c  = q * 256 + tid;              // qword id 0..2047
            int sl = c >> 6;                     // source slice 0..31
            int l  = c & 63;                     // b=l>>2, u4=l&3
            *(unsigned long long*)&a_lds[l >> 2][sl * 16 + (l & 3) * 4] = stg[q];
        }
        __syncthreads();

        // --- MFMA: M=16 (batch), N=16 (units), K=512 ---
        f32x4 acc = (f32x4)0.0f;
#pragma unroll
        for (int s = 0; s < 16; ++s) {
            bf16x8 af = *(const bf16x8*)&a_lds[l16][s * 32 + quad * 8];
            acc = __builtin_amdgcn_mfma_f32_16x16x32_bf16(af, bq[s], acc, 0, 0, 0);
        }
        // fold xW, write gate exchange (D layout: row=quad*4+r, col=l16)
#pragma unroll
        for (int r = 0; r < 4; ++r)
            gbuf[wave][quad * 4 + r][l16] = acc[r] + xg[r];
        __syncthreads();

        // --- gates: thread (bt, ut), fp32 state in register ---
        {
            float gu = gbuf[0][bt][ut];
            float gf = gbuf[1][bt][ut];
            float go = gbuf[2][bt][ut];
            float gc = gbuf[3][bt][ut];
            float su = 1.f / (1.f + __expf(-gu));
            float sf = 1.f / (1.f + __expf(-gf));
            float so = 1.f / (1.f + __expf(-go));
            float e2 = __expf(2.f * gc);
            float tc = 1.f - 2.f / (e2 + 1.f);           // tanh(gc)
            float cc = su * tc + sf * aown;               // forget * a_{t-1}
            float ec = __expf(2.f * cc);
            float th = 1.f - 2.f / (ec + 1.f);            // tanh(c)
            float a  = so * th;
            aown = a;
            out[((size_t)t * NB + b0 + bt) * HID + j0 + ut] = a;
            alds_out[bt][ut] = f2bf(a);
        }
        __syncthreads();

        // --- publish: wave 0 packs 512 B contiguous + flag ---
        if (wave == 0) {
            unsigned long long pk =
                *(unsigned long long*)&alds_out[lane >> 2][(lane & 3) * 4];
            const size_t wbase =
                ((size_t)((t + 1) & 1) * BB + i_blk) * (NSL * 64) +
                (size_t)j_sl * 64;
            __hip_atomic_store(&abq[wbase + lane], pk,
                               __ATOMIC_RELAXED, __HIP_MEMORY_SCOPE_AGENT);
            __asm__ __volatile__("s_waitcnt vmcnt(0)" ::: "memory");
            if (lane == 0)
                __hip_atomic_store(&gflags[j_sl * FLAG_STRIDE], (unsigned)(t + 2),
                                   __ATOMIC_RELAXED, __HIP_MEMORY_SCOPE_AGENT);
        }
    }
}

// ---------------------------------------------------------------------------
extern "C" void kernel_launch(void* const* d_in, const int* in_sizes, int n_in,
                              void* d_out, int out_size, void* d_ws, size_t ws_size,
                              hipStream_t stream) {
    (void)in_sizes; (void)n_in; (void)out_size; (void)ws_size;
    const float* x    = (const float*)d_in[0];   // [T,B,I]
    const float* a0   = (const float*)d_in[1];   // [B,H]
    const float* W    = (const float*)d_in[2];   // [I,4H]
    const float* U    = (const float*)d_in[3];   // [H,4H]
    const float* bias = (const float*)d_in[4];   // [4H]
    float* out = (float*)d_out;

    char* ws = (char*)d_ws;
    unsigned short* xbf  = (unsigned short*)(ws);                 // 33,554,432 B
    unsigned short* Wt   = (unsigned short*)(ws + 33554432);      //  2,097,152 B
    unsigned short* Ut   = (unsigned short*)(ws + 35651584);      //  2,097,152 B
    unsigned short* xWp  = (unsigned short*)(ws + 37748736);      // 134,217,728 B
    unsigned short* abuf = (unsigned short*)(ws + 171966464);     //    131,072 B
    unsigned*       flags= (unsigned*)(ws + 172097536);           //      4,096 B

    cast_x_kernel<<<16384, 256, 0, stream>>>(x, xbf, flags);
    transpose_cast<<<dim3(32, 8), 256, 0, stream>>>(W, Wt);
    transpose_cast<<<dim3(32, 8), 256, 0, stream>>>(U, Ut);
    gemm_xw<<<dim3(256, 16), 256, 0, stream>>>(xbf, Wt, bias, xWp);
    lstm_rec<<<BB * NSL, 256, 0, stream>>>(xWp, Ut, a0, out, abuf, flags);
}